// Round 19
// baseline (220.642 us; speedup 1.0000x reference)
//
#include <hip/hip_runtime.h>
#include <cstdint>
#include <cstddef>

#define C_DIM 256
#define N_PIX 10000
#define B_SZ 16

// ---------------- k_prep_wpe (R15-exact) ------------------------------------------------
__global__ __launch_bounds__(256) void k_prep_wpe(
    const float* __restrict__ pe,
    const float* __restrict__ Wc, const float* __restrict__ Wb,
    float* __restrict__ wpe) {
  int tid = threadIdx.x;
  int bid = blockIdx.x;                 // 60 blocks
  int o = bid / 10;
  int p = (bid % 10) * 256 + tid;
  if (p >= 2500) return;
  const float* W = (o < 2) ? (Wc + o * C_DIM) : (Wb + (o - 2) * C_DIM);
  float acc = 0.f;
#pragma unroll 8
  for (int c = 0; c < C_DIM; ++c) acc = fmaf(W[c], pe[c * 2500 + p], acc);
  wpe[o * 2500 + p] = acc;
}

// ---------------- k_heads4 (R15-exact) --------------------------------------------------
__global__ __launch_bounds__(256, 4) void k_heads4(
    const float* __restrict__ x, const float* __restrict__ wpe,
    const float* __restrict__ Wc, const float* __restrict__ bc,
    const float* __restrict__ Wb, const float* __restrict__ bb,
    float* __restrict__ cls, float* __restrict__ bbox, float* __restrict__ conf) {
  int tid = threadIdx.x;
  int b = blockIdx.y;
  int n = blockIdx.x * 256 + tid;
  if (n >= N_PIX) return;
  const float* xb = x + (size_t)b * C_DIM * N_PIX + n;
  const float* w1p = Wc + C_DIM;
  const float* w2p = Wb;
  const float* w3p = Wb + C_DIM;
  const float* w4p = Wb + 2 * C_DIM;
  const float* w5p = Wb + 3 * C_DIM;
  float a0 = 0.f, a1 = 0.f, a2 = 0.f, a3 = 0.f, a4 = 0.f, a5 = 0.f;
  for (int c = 0; c < C_DIM; c += 16) {
    float xv[16];
#pragma unroll
    for (int j = 0; j < 16; ++j) xv[j] = xb[(size_t)(c + j) * N_PIX];
#pragma unroll
    for (int j = 0; j < 16; ++j) {
      float v = xv[j];
      a0 = fmaf(Wc[c + j],  v, a0);
      a1 = fmaf(w1p[c + j], v, a1);
      a2 = fmaf(w2p[c + j], v, a2);
      a3 = fmaf(w3p[c + j], v, a3);
      a4 = fmaf(w4p[c + j], v, a4);
      a5 = fmaf(w5p[c + j], v, a5);
    }
  }
  int y = n / 100, xq = n % 100;
  float sy = fminf(fmaxf((y + 0.5f) * 0.5f - 0.5f, 0.0f), 49.0f);
  float sx = fminf(fmaxf((xq + 0.5f) * 0.5f - 0.5f, 0.0f), 49.0f);
  int y0 = (int)floorf(sy); int y1 = min(y0 + 1, 49); float ty = sy - (float)y0;
  int x0i = (int)floorf(sx); int x1i = min(x0i + 1, 49); float tx = sx - (float)x0i;
  float pd[6];
#pragma unroll
  for (int o = 0; o < 6; ++o) {
    const float* m = wpe + o * 2500;
    float v00 = m[y0 * 50 + x0i], v01 = m[y0 * 50 + x1i];
    float v10 = m[y1 * 50 + x0i], v11 = m[y1 * 50 + x1i];
    float r0 = v00 * (1.0f - ty) + v10 * ty;
    float r1 = v01 * (1.0f - ty) + v11 * ty;
    pd[o] = r0 * (1.0f - tx) + r1 * tx;
  }
  float c0 = a0 + pd[0] + bc[0];
  float c1 = a1 + pd[1] + bc[1];
  float b0 = a2 + pd[2] + bb[0];
  float b1 = a3 + pd[3] + bb[1];
  float b2 = a4 + pd[4] + bb[2];
  float b3 = a5 + pd[5] + bb[3];
  size_t nb = (size_t)b * N_PIX + n;
  float2 cv; cv.x = c0; cv.y = c1;
  *(float2*)(cls + nb * 2) = cv;
  float4 bv; bv.x = b0; bv.y = b1; bv.z = b2; bv.w = b3;
  *(float4*)(bbox + nb * 4) = bv;
  float m0 = fmaxf(c0, c1);
  float e0 = expf(c0 - m0), e1 = expf(c1 - m0);
  conf[nb] = e1 / (e0 + e1);
}

// ---------------- k_topk_plus (R15-exact): blocks 0..15 top-k, 16..111 wT transpose -----
__global__ __launch_bounds__(1024) void k_topk_plus(
    const float* __restrict__ conf, int* __restrict__ idx_out,
    const float* __restrict__ dW1, const float* __restrict__ dW2, const float* __restrict__ dW3,
    const float* __restrict__ rW1, const float* __restrict__ rW2, const float* __restrict__ rW3,
    float* __restrict__ wT) {
  int tid = threadIdx.x;
  int bid = blockIdx.x;
  if (bid >= 16) {
    __shared__ float tile[64][65];
    int t = bid - 16;                 // 96 blocks: 6 matrices x 16 (64x64) tiles
    int m = t >> 4;
    int tl = t & 15;
    int ty = tl >> 2, tx = tl & 3;
    const float* W;
    switch (m) {
      case 0: W = dW1; break;
      case 1: W = dW2; break;
      case 2: W = dW3; break;
      case 3: W = rW1; break;
      case 4: W = rW2; break;
      default: W = rW3; break;
    }
    int lane = tid & 63, rg = tid >> 6;       // 16 row-groups
    for (int rr = rg; rr < 64; rr += 16)
      tile[rr][lane] = W[(size_t)(ty * 64 + rr) * 256 + tx * 64 + lane];
    __syncthreads();
    for (int rr = rg; rr < 64; rr += 16)
      wT[(size_t)m * 65536 + (size_t)(tx * 64 + rr) * 256 + ty * 64 + lane] = tile[lane][rr];
    return;
  }
  __shared__ unsigned int ord[N_PIX];
  __shared__ unsigned int whist[16][256];
  __shared__ unsigned int sfx[256];
  __shared__ unsigned long long cand[512];
  __shared__ unsigned int s_cnt, s_prefix, s_ncand;
  int wv = tid >> 6;
  int b = bid;
  const float* cb = conf + (size_t)b * N_PIX;
  for (int i = tid; i < N_PIX; i += 1024) {
    unsigned int u = __float_as_uint(cb[i]);
    ord[i] = (u & 0x80000000u) ? ~u : (u | 0x80000000u);
  }
  unsigned int prefix = 0, cnt_gt = 0;
  for (int pass = 0; pass < 4; ++pass) {
    int sh = 24 - 8 * pass;
    for (int i = tid; i < 16 * 256; i += 1024) ((unsigned int*)whist)[i] = 0;
    __syncthreads();
    unsigned int himask = (pass == 0) ? 0u : (0xFFFFFFFFu << (sh + 8));
    for (int i = tid; i < N_PIX; i += 1024) {
      unsigned int o = ord[i];
      if ((o & himask) == prefix) atomicAdd(&whist[wv][(o >> sh) & 255u], 1u);
    }
    __syncthreads();
    if (tid < 256) {
      unsigned int s = 0;
#pragma unroll
      for (int w2 = 0; w2 < 16; ++w2) s += whist[w2][tid];
      sfx[tid] = s;
    }
    __syncthreads();
#pragma unroll
    for (int off = 1; off < 256; off <<= 1) {
      unsigned int add = 0;
      if (tid < 256 && tid + off < 256) add = sfx[tid + off];
      __syncthreads();
      if (tid < 256) sfx[tid] += add;
      __syncthreads();
    }
    if (tid < 256) {
      unsigned int Sv = sfx[tid];
      unsigned int Sn = (tid < 255) ? sfx[tid + 1] : 0u;
      if (cnt_gt + Sv >= 100u && (tid == 255 || cnt_gt + Sn < 100u)) {
        s_cnt = cnt_gt + Sn;
        s_prefix = prefix | ((unsigned int)tid << sh);
      }
    }
    __syncthreads();
    cnt_gt = s_cnt; prefix = s_prefix;
    __syncthreads();
  }
  if (tid == 0) s_ncand = 0;
  __syncthreads();
  unsigned int T = prefix;
  for (int i = tid; i < N_PIX; i += 1024) {
    unsigned int o = ord[i];
    if (o >= T) {
      unsigned int k = atomicAdd(&s_ncand, 1u);
      if (k < 512u)
        cand[k] = ((unsigned long long)o << 32) |
                  (unsigned long long)(0xFFFFFFFFu - (unsigned int)i);
    }
  }
  __syncthreads();
  unsigned int nc = s_ncand > 512u ? 512u : s_ncand;
  for (int i = tid; i < 512; i += 1024)
    if ((unsigned int)i >= nc) cand[i] = 0ull;
  __syncthreads();
  for (unsigned int k = 2; k <= 512; k <<= 1) {
    for (unsigned int j = k >> 1; j > 0; j >>= 1) {
      if (tid < 512) {
        unsigned int i = (unsigned int)tid, ixj = i ^ j;
        if (ixj > i) {
          unsigned long long a = cand[i], c2 = cand[ixj];
          bool up = ((i & k) == 0);
          if ((a > c2) == up) { cand[i] = c2; cand[ixj] = a; }
        }
      }
      __syncthreads();
    }
  }
  if (tid < 100) {
    unsigned long long key = cand[511 - tid];
    idx_out[b * 100 + tid] = (int)(0xFFFFFFFFu - (unsigned int)(key & 0xFFFFFFFFull));
  }
}

// ---------------- k_mlp6 (R15-exact) ----------------------------------------------------
#define R8 8

__device__ __forceinline__ float pos_bilinear(const float* __restrict__ pe, int c, int n) {
  int y = n / 100, xq = n % 100;
  float sy = fminf(fmaxf((y + 0.5f) * 0.5f - 0.5f, 0.0f), 49.0f);
  float sx = fminf(fmaxf((xq + 0.5f) * 0.5f - 0.5f, 0.0f), 49.0f);
  int y0 = (int)floorf(sy); int y1 = min(y0 + 1, 49); float ty = sy - (float)y0;
  int x0i = (int)floorf(sx); int x1i = min(x0i + 1, 49); float tx = sx - (float)x0i;
  const float* p = pe + (size_t)c * 2500;
  float v00 = p[y0 * 50 + x0i], v01 = p[y0 * 50 + x1i];
  float v10 = p[y1 * 50 + x0i], v11 = p[y1 * 50 + x1i];
  float rr0 = v00 * (1.0f - ty) + v10 * ty;
  float rr1 = v01 * (1.0f - ty) + v11 * ty;
  return rr0 * (1.0f - tx) + rr1 * tx;
}

__device__ __forceinline__ void mlp6_layer(const float (*in)[C_DIM], float (*outb)[C_DIM],
    float (*red)[R8][C_DIM], const float* __restrict__ Wl, const float* __restrict__ bias,
    bool relu, int og, int rg, int tid) {
  float4 acc[R8];
#pragma unroll
  for (int r = 0; r < R8; ++r) { acc[r].x = 0.f; acc[r].y = 0.f; acc[r].z = 0.f; acc[r].w = 0.f; }
  int c0 = rg * 32;
#pragma unroll 2
  for (int ci = 0; ci < 32; ci += 4) {
    int c = c0 + ci;
    float4 w0 = *(const float4*)(Wl + (size_t)(c + 0) * C_DIM + og * 4);
    float4 w1 = *(const float4*)(Wl + (size_t)(c + 1) * C_DIM + og * 4);
    float4 w2 = *(const float4*)(Wl + (size_t)(c + 2) * C_DIM + og * 4);
    float4 w3 = *(const float4*)(Wl + (size_t)(c + 3) * C_DIM + og * 4);
#pragma unroll
    for (int r = 0; r < R8; ++r) {
      float4 iv = *(const float4*)(&in[r][c]);
      acc[r].x = fmaf(w0.x, iv.x, acc[r].x); acc[r].y = fmaf(w0.y, iv.x, acc[r].y);
      acc[r].z = fmaf(w0.z, iv.x, acc[r].z); acc[r].w = fmaf(w0.w, iv.x, acc[r].w);
      acc[r].x = fmaf(w1.x, iv.y, acc[r].x); acc[r].y = fmaf(w1.y, iv.y, acc[r].y);
      acc[r].z = fmaf(w1.z, iv.y, acc[r].z); acc[r].w = fmaf(w1.w, iv.y, acc[r].w);
      acc[r].x = fmaf(w2.x, iv.z, acc[r].x); acc[r].y = fmaf(w2.y, iv.z, acc[r].y);
      acc[r].z = fmaf(w2.z, iv.z, acc[r].z); acc[r].w = fmaf(w2.w, iv.z, acc[r].w);
      acc[r].x = fmaf(w3.x, iv.w, acc[r].x); acc[r].y = fmaf(w3.y, iv.w, acc[r].y);
      acc[r].z = fmaf(w3.z, iv.w, acc[r].z); acc[r].w = fmaf(w3.w, iv.w, acc[r].w);
    }
  }
#pragma unroll
  for (int r = 0; r < R8; ++r) *(float4*)(&red[rg][r][og * 4]) = acc[r];
  __syncthreads();
#pragma unroll
  for (int k = 0; k < 4; ++k) {
    int e = tid + k * 512;
    int r = e >> 8, o = e & 255;
    float s = bias[o];
#pragma unroll
    for (int g = 0; g < 8; ++g) s += red[g][r][o];
    outb[r][o] = relu ? fmaxf(s, 0.f) : s;
  }
  __syncthreads();
}

__global__ __launch_bounds__(512, 2) void k_mlp6(
    const float* __restrict__ x, const float* __restrict__ pe, const int* __restrict__ idx,
    const float* __restrict__ wT,
    const float* __restrict__ db1, const float* __restrict__ db2, const float* __restrict__ db3,
    const float* __restrict__ rb1, const float* __restrict__ rb2, const float* __restrict__ rb3,
    const float* __restrict__ det_q, const float* __restrict__ rec_q,
    float* __restrict__ det, float* __restrict__ rec) {
  __shared__ float actA[R8][C_DIM];
  __shared__ float actB[R8][C_DIM];
  __shared__ float red[8][R8][C_DIM];
  int tid = threadIdx.x;
  int og = tid & 63, rg = tid >> 6;
  int base = blockIdx.x * R8;
  bool is_det = base < 1600;
  const float *W1, *W2, *W3, *B1, *B2, *B3;
  if (is_det) {
    W1 = wT;          W2 = wT + 65536;  W3 = wT + 131072;
    B1 = db1; B2 = db2; B3 = db3;
  } else {
    W1 = wT + 196608; W2 = wT + 262144; W3 = wT + 327680;
    B1 = rb1; B2 = rb2; B3 = rb3;
  }
#pragma unroll
  for (int k = 0; k < 4; ++k) {
    int e = tid + k * 512;
    int r = e >> 8, c = e & 255;
    int rowid = base + r;
    int b, rr;
    if (rowid < 1600) { b = rowid / 100; rr = rowid % 100; }
    else { int t2 = rowid - 1600; b = t2 / 25; rr = t2 % 25; }
    int n = idx[b * 100 + rr];
    actA[r][c] = x[((size_t)b * C_DIM + c) * N_PIX + n] + pos_bilinear(pe, c, n);
  }
  __syncthreads();
  mlp6_layer(actA, actB, red, W1, B1, true,  og, rg, tid);
  mlp6_layer(actB, actA, red, W2, B2, true,  og, rg, tid);
  mlp6_layer(actA, actB, red, W3, B3, false, og, rg, tid);
#pragma unroll
  for (int k = 0; k < 4; ++k) {
    int e = tid + k * 512;
    int r = e >> 8, o = e & 255;
    int rowid = base + r;
    if (rowid < 1600) {
      int rr = rowid % 100;
      det[(size_t)rowid * C_DIM + o] = actB[r][o] + det_q[rr * C_DIM + o];
    } else {
      int t2 = rowid - 1600; int rr = t2 % 25;
      rec[(size_t)t2 * C_DIM + o] = actB[r][o] + rec_q[rr * C_DIM + o];
    }
  }
}

extern "C" void kernel_launch(void* const* d_in, const int* in_sizes, int n_in,
                              void* d_out, int out_size, void* d_ws, size_t ws_size,
                              hipStream_t stream) {
  const float* x     = (const float*)d_in[0];
  const float* Wc    = (const float*)d_in[1];
  const float* bc    = (const float*)d_in[2];
  const float* Wb    = (const float*)d_in[3];
  const float* bb    = (const float*)d_in[4];
  const float* dW1   = (const float*)d_in[5];
  const float* db1   = (const float*)d_in[6];
  const float* dW2   = (const float*)d_in[7];
  const float* db2   = (const float*)d_in[8];
  const float* dW3   = (const float*)d_in[9];
  const float* db3   = (const float*)d_in[10];
  const float* rW1   = (const float*)d_in[11];
  const float* rb1   = (const float*)d_in[12];
  const float* rW2   = (const float*)d_in[13];
  const float* rb2   = (const float*)d_in[14];
  const float* rW3   = (const float*)d_in[15];
  const float* rb3   = (const float*)d_in[16];
  const float* det_q = (const float*)d_in[17];
  const float* rec_q = (const float*)d_in[18];
  const float* pos_e = (const float*)d_in[19];

  float* out  = (float*)d_out;
  float* det  = out;                // [16,100,256]
  float* rec  = out + 409600;       // [16, 25,256]
  float* cls  = out + 512000;       // [16,10000,2]
  float* bbox = out + 832000;       // [16,10000,4]

  // ws layout (bytes): wT @0 (1572864) | conf @1572864 (640000) | idx @2212864 | wpe @2221056
  char* wsb = (char*)d_ws;
  float* wT   = (float*)wsb;
  float* conf = (float*)(wsb + 1572864);
  int*   idx  = (int*)(wsb + 2212864);
  float* wpe  = (float*)(wsb + 2221056);

  k_prep_wpe<<<60, 256, 0, stream>>>(pos_e, Wc, Wb, wpe);
  k_heads4<<<dim3(40, B_SZ), 256, 0, stream>>>(x, wpe, Wc, bc, Wb, bb, cls, bbox, conf);
  // MEASUREMENT: k_topk_plus launched 6x (idempotent: same idx, same wT every time).
  // topk_warm = (T - 106.8)/5 - gap.
  for (int rep = 0; rep < 6; ++rep) {
    k_topk_plus<<<112, 1024, 0, stream>>>(conf, idx, dW1, dW2, dW3, rW1, rW2, rW3, wT);
  }
  k_mlp6<<<250, 512, 0, stream>>>(x, pos_e, idx, wT,
                                  db1, db2, db3, rb1, rb2, rb3,
                                  det_q, rec_q, det, rec);
}

// Round 20
// 107.995 us; speedup vs baseline: 2.0431x; 2.0431x over previous
//
#include <hip/hip_runtime.h>
#include <cstdint>
#include <cstddef>

#define C_DIM 256
#define N_PIX 10000
#define B_SZ 16

// ---------------- k_prep_wpe (R15-exact) ------------------------------------------------
__global__ __launch_bounds__(256) void k_prep_wpe(
    const float* __restrict__ pe,
    const float* __restrict__ Wc, const float* __restrict__ Wb,
    float* __restrict__ wpe) {
  int tid = threadIdx.x;
  int bid = blockIdx.x;                 // 60 blocks
  int o = bid / 10;
  int p = (bid % 10) * 256 + tid;
  if (p >= 2500) return;
  const float* W = (o < 2) ? (Wc + o * C_DIM) : (Wb + (o - 2) * C_DIM);
  float acc = 0.f;
#pragma unroll 8
  for (int c = 0; c < C_DIM; ++c) acc = fmaf(W[c], pe[c * 2500 + p], acc);
  wpe[o * 2500 + p] = acc;
}

// ---------------- k_heads4 (R15-exact) --------------------------------------------------
__global__ __launch_bounds__(256, 4) void k_heads4(
    const float* __restrict__ x, const float* __restrict__ wpe,
    const float* __restrict__ Wc, const float* __restrict__ bc,
    const float* __restrict__ Wb, const float* __restrict__ bb,
    float* __restrict__ cls, float* __restrict__ bbox, float* __restrict__ conf) {
  int tid = threadIdx.x;
  int b = blockIdx.y;
  int n = blockIdx.x * 256 + tid;
  if (n >= N_PIX) return;
  const float* xb = x + (size_t)b * C_DIM * N_PIX + n;
  const float* w1p = Wc + C_DIM;
  const float* w2p = Wb;
  const float* w3p = Wb + C_DIM;
  const float* w4p = Wb + 2 * C_DIM;
  const float* w5p = Wb + 3 * C_DIM;
  float a0 = 0.f, a1 = 0.f, a2 = 0.f, a3 = 0.f, a4 = 0.f, a5 = 0.f;
  for (int c = 0; c < C_DIM; c += 16) {
    float xv[16];
#pragma unroll
    for (int j = 0; j < 16; ++j) xv[j] = xb[(size_t)(c + j) * N_PIX];
#pragma unroll
    for (int j = 0; j < 16; ++j) {
      float v = xv[j];
      a0 = fmaf(Wc[c + j],  v, a0);
      a1 = fmaf(w1p[c + j], v, a1);
      a2 = fmaf(w2p[c + j], v, a2);
      a3 = fmaf(w3p[c + j], v, a3);
      a4 = fmaf(w4p[c + j], v, a4);
      a5 = fmaf(w5p[c + j], v, a5);
    }
  }
  int y = n / 100, xq = n % 100;
  float sy = fminf(fmaxf((y + 0.5f) * 0.5f - 0.5f, 0.0f), 49.0f);
  float sx = fminf(fmaxf((xq + 0.5f) * 0.5f - 0.5f, 0.0f), 49.0f);
  int y0 = (int)floorf(sy); int y1 = min(y0 + 1, 49); float ty = sy - (float)y0;
  int x0i = (int)floorf(sx); int x1i = min(x0i + 1, 49); float tx = sx - (float)x0i;
  float pd[6];
#pragma unroll
  for (int o = 0; o < 6; ++o) {
    const float* m = wpe + o * 2500;
    float v00 = m[y0 * 50 + x0i], v01 = m[y0 * 50 + x1i];
    float v10 = m[y1 * 50 + x0i], v11 = m[y1 * 50 + x1i];
    float r0 = v00 * (1.0f - ty) + v10 * ty;
    float r1 = v01 * (1.0f - ty) + v11 * ty;
    pd[o] = r0 * (1.0f - tx) + r1 * tx;
  }
  float c0 = a0 + pd[0] + bc[0];
  float c1 = a1 + pd[1] + bc[1];
  float b0 = a2 + pd[2] + bb[0];
  float b1 = a3 + pd[3] + bb[1];
  float b2 = a4 + pd[4] + bb[2];
  float b3 = a5 + pd[5] + bb[3];
  size_t nb = (size_t)b * N_PIX + n;
  float2 cv; cv.x = c0; cv.y = c1;
  *(float2*)(cls + nb * 2) = cv;
  float4 bv; bv.x = b0; bv.y = b1; bv.z = b2; bv.w = b3;
  *(float4*)(bbox + nb * 4) = bv;
  float m0 = fmaxf(c0, c1);
  float e0 = expf(c0 - m0), e1 = expf(c1 - m0);
  conf[nb] = e1 / (e0 + e1);
}

// ---------------- k_topk_plus: R15 structure; pass-0 + collection ballot-aggregated -----
__global__ __launch_bounds__(1024) void k_topk_plus(
    const float* __restrict__ conf, int* __restrict__ idx_out,
    const float* __restrict__ dW1, const float* __restrict__ dW2, const float* __restrict__ dW3,
    const float* __restrict__ rW1, const float* __restrict__ rW2, const float* __restrict__ rW3,
    float* __restrict__ wT) {
  int tid = threadIdx.x;
  int bid = blockIdx.x;
  if (bid >= 16) {
    __shared__ float tile[64][65];
    int t = bid - 16;                 // 96 blocks: 6 matrices x 16 (64x64) tiles
    int m = t >> 4;
    int tl = t & 15;
    int ty = tl >> 2, tx = tl & 3;
    const float* W;
    switch (m) {
      case 0: W = dW1; break;
      case 1: W = dW2; break;
      case 2: W = dW3; break;
      case 3: W = rW1; break;
      case 4: W = rW2; break;
      default: W = rW3; break;
    }
    int lane = tid & 63, rg = tid >> 6;       // 16 row-groups
    for (int rr = rg; rr < 64; rr += 16)
      tile[rr][lane] = W[(size_t)(ty * 64 + rr) * 256 + tx * 64 + lane];
    __syncthreads();
    for (int rr = rg; rr < 64; rr += 16)
      wT[(size_t)m * 65536 + (size_t)(tx * 64 + rr) * 256 + ty * 64 + lane] = tile[lane][rr];
    return;
  }
  __shared__ unsigned int ord[N_PIX];
  __shared__ unsigned int whist[16][256];
  __shared__ unsigned int sfx[256];
  __shared__ unsigned long long cand[512];
  __shared__ unsigned int s_cnt, s_prefix, s_ncand;
  int wv = tid >> 6;
  int lane = tid & 63;
  int b = bid;
  const float* cb = conf + (size_t)b * N_PIX;
  for (int i = tid; i < N_PIX; i += 1024) {
    unsigned int u = __float_as_uint(cb[i]);
    ord[i] = (u & 0x80000000u) ? ~u : (u | 0x80000000u);
  }
  unsigned int prefix = 0, cnt_gt = 0;
  for (int pass = 0; pass < 4; ++pass) {
    int sh = 24 - 8 * pass;
    for (int i = tid; i < 16 * 256; i += 1024) ((unsigned int*)whist)[i] = 0;
    __syncthreads();
    if (pass == 0) {
      // exponent bins are concentrated (conf in (0,1)) -> ballot-aggregate:
      // one LDS atomic per DISTINCT bin per wave-chunk (~2-4 iterations).
      for (int ib = 0; ib < 10; ++ib) {
        int i = tid + ib * 1024;
        bool valid = (i < N_PIX);
        unsigned int o = valid ? ord[i] : 0u;
        unsigned int bin = (o >> 24) & 255u;
        unsigned long long rem = __ballot(valid);
        while (rem) {
          int leader = (int)(__ffsll((unsigned long long)rem) - 1);
          unsigned int lb = __shfl(bin, leader);
          unsigned long long mk = __ballot(valid && (bin == lb));
          if (lane == leader) atomicAdd(&whist[wv][lb], (unsigned int)__popcll(mk));
          rem &= ~mk;
        }
      }
    } else {
      // mantissa bins ~uniform -> plain per-wave atomics are conflict-free.
      unsigned int himask = 0xFFFFFFFFu << (sh + 8);
      for (int i = tid; i < N_PIX; i += 1024) {
        unsigned int o = ord[i];
        if ((o & himask) == prefix) atomicAdd(&whist[wv][(o >> sh) & 255u], 1u);
      }
    }
    __syncthreads();
    if (tid < 256) {
      unsigned int s = 0;
#pragma unroll
      for (int w2 = 0; w2 < 16; ++w2) s += whist[w2][tid];
      sfx[tid] = s;
    }
    __syncthreads();
#pragma unroll
    for (int off = 1; off < 256; off <<= 1) {
      unsigned int add = 0;
      if (tid < 256 && tid + off < 256) add = sfx[tid + off];
      __syncthreads();
      if (tid < 256) sfx[tid] += add;
      __syncthreads();
    }
    if (tid < 256) {
      unsigned int Sv = sfx[tid];
      unsigned int Sn = (tid < 255) ? sfx[tid + 1] : 0u;
      if (cnt_gt + Sv >= 100u && (tid == 255 || cnt_gt + Sn < 100u)) {
        s_cnt = cnt_gt + Sn;
        s_prefix = prefix | ((unsigned int)tid << sh);
      }
    }
    __syncthreads();
    cnt_gt = s_cnt; prefix = s_prefix;
    __syncthreads();
  }
  if (tid == 0) s_ncand = 0;
  __syncthreads();
  unsigned int T = prefix;
  for (int ib = 0; ib < 10; ++ib) {
    int i = tid + ib * 1024;
    bool want = (i < N_PIX) && (ord[i] >= T);
    unsigned long long mk = __ballot(want);
    if (mk) {
      int leader = (int)(__ffsll((unsigned long long)mk) - 1);
      unsigned int base0 = 0;
      if (lane == leader) base0 = atomicAdd(&s_ncand, (unsigned int)__popcll(mk));
      base0 = __shfl(base0, leader);
      unsigned int off = (unsigned int)__popcll(mk & ((1ull << lane) - 1ull));
      if (want) {
        unsigned int k = base0 + off;
        if (k < 512u)
          cand[k] = ((unsigned long long)ord[i] << 32) |
                    (unsigned long long)(0xFFFFFFFFu - (unsigned int)i);
      }
    }
  }
  __syncthreads();
  unsigned int nc = s_ncand > 512u ? 512u : s_ncand;
  for (int i = tid; i < 512; i += 1024)
    if ((unsigned int)i >= nc) cand[i] = 0ull;
  __syncthreads();
  for (unsigned int k = 2; k <= 512; k <<= 1) {
    for (unsigned int j = k >> 1; j > 0; j >>= 1) {
      if (tid < 512) {
        unsigned int i = (unsigned int)tid, ixj = i ^ j;
        if (ixj > i) {
          unsigned long long a = cand[i], c2 = cand[ixj];
          bool up = ((i & k) == 0);
          if ((a > c2) == up) { cand[i] = c2; cand[ixj] = a; }
        }
      }
      __syncthreads();
    }
  }
  if (tid < 100) {
    unsigned long long key = cand[511 - tid];
    idx_out[b * 100 + tid] = (int)(0xFFFFFFFFu - (unsigned int)(key & 0xFFFFFFFFull));
  }
}

// ---------------- k_mlp6 (R15-exact) ----------------------------------------------------
#define R8 8

__device__ __forceinline__ float pos_bilinear(const float* __restrict__ pe, int c, int n) {
  int y = n / 100, xq = n % 100;
  float sy = fminf(fmaxf((y + 0.5f) * 0.5f - 0.5f, 0.0f), 49.0f);
  float sx = fminf(fmaxf((xq + 0.5f) * 0.5f - 0.5f, 0.0f), 49.0f);
  int y0 = (int)floorf(sy); int y1 = min(y0 + 1, 49); float ty = sy - (float)y0;
  int x0i = (int)floorf(sx); int x1i = min(x0i + 1, 49); float tx = sx - (float)x0i;
  const float* p = pe + (size_t)c * 2500;
  float v00 = p[y0 * 50 + x0i], v01 = p[y0 * 50 + x1i];
  float v10 = p[y1 * 50 + x0i], v11 = p[y1 * 50 + x1i];
  float rr0 = v00 * (1.0f - ty) + v10 * ty;
  float rr1 = v01 * (1.0f - ty) + v11 * ty;
  return rr0 * (1.0f - tx) + rr1 * tx;
}

__device__ __forceinline__ void mlp6_layer(const float (*in)[C_DIM], float (*outb)[C_DIM],
    float (*red)[R8][C_DIM], const float* __restrict__ Wl, const float* __restrict__ bias,
    bool relu, int og, int rg, int tid) {
  float4 acc[R8];
#pragma unroll
  for (int r = 0; r < R8; ++r) { acc[r].x = 0.f; acc[r].y = 0.f; acc[r].z = 0.f; acc[r].w = 0.f; }
  int c0 = rg * 32;
#pragma unroll 2
  for (int ci = 0; ci < 32; ci += 4) {
    int c = c0 + ci;
    float4 w0 = *(const float4*)(Wl + (size_t)(c + 0) * C_DIM + og * 4);
    float4 w1 = *(const float4*)(Wl + (size_t)(c + 1) * C_DIM + og * 4);
    float4 w2 = *(const float4*)(Wl + (size_t)(c + 2) * C_DIM + og * 4);
    float4 w3 = *(const float4*)(Wl + (size_t)(c + 3) * C_DIM + og * 4);
#pragma unroll
    for (int r = 0; r < R8; ++r) {
      float4 iv = *(const float4*)(&in[r][c]);
      acc[r].x = fmaf(w0.x, iv.x, acc[r].x); acc[r].y = fmaf(w0.y, iv.x, acc[r].y);
      acc[r].z = fmaf(w0.z, iv.x, acc[r].z); acc[r].w = fmaf(w0.w, iv.x, acc[r].w);
      acc[r].x = fmaf(w1.x, iv.y, acc[r].x); acc[r].y = fmaf(w1.y, iv.y, acc[r].y);
      acc[r].z = fmaf(w1.z, iv.y, acc[r].z); acc[r].w = fmaf(w1.w, iv.y, acc[r].w);
      acc[r].x = fmaf(w2.x, iv.z, acc[r].x); acc[r].y = fmaf(w2.y, iv.z, acc[r].y);
      acc[r].z = fmaf(w2.z, iv.z, acc[r].z); acc[r].w = fmaf(w2.w, iv.z, acc[r].w);
      acc[r].x = fmaf(w3.x, iv.w, acc[r].x); acc[r].y = fmaf(w3.y, iv.w, acc[r].y);
      acc[r].z = fmaf(w3.z, iv.w, acc[r].z); acc[r].w = fmaf(w3.w, iv.w, acc[r].w);
    }
  }
#pragma unroll
  for (int r = 0; r < R8; ++r) *(float4*)(&red[rg][r][og * 4]) = acc[r];
  __syncthreads();
#pragma unroll
  for (int k = 0; k < 4; ++k) {
    int e = tid + k * 512;
    int r = e >> 8, o = e & 255;
    float s = bias[o];
#pragma unroll
    for (int g = 0; g < 8; ++g) s += red[g][r][o];
    outb[r][o] = relu ? fmaxf(s, 0.f) : s;
  }
  __syncthreads();
}

__global__ __launch_bounds__(512, 2) void k_mlp6(
    const float* __restrict__ x, const float* __restrict__ pe, const int* __restrict__ idx,
    const float* __restrict__ wT,
    const float* __restrict__ db1, const float* __restrict__ db2, const float* __restrict__ db3,
    const float* __restrict__ rb1, const float* __restrict__ rb2, const float* __restrict__ rb3,
    const float* __restrict__ det_q, const float* __restrict__ rec_q,
    float* __restrict__ det, float* __restrict__ rec) {
  __shared__ float actA[R8][C_DIM];
  __shared__ float actB[R8][C_DIM];
  __shared__ float red[8][R8][C_DIM];
  int tid = threadIdx.x;
  int og = tid & 63, rg = tid >> 6;
  int base = blockIdx.x * R8;
  bool is_det = base < 1600;
  const float *W1, *W2, *W3, *B1, *B2, *B3;
  if (is_det) {
    W1 = wT;          W2 = wT + 65536;  W3 = wT + 131072;
    B1 = db1; B2 = db2; B3 = db3;
  } else {
    W1 = wT + 196608; W2 = wT + 262144; W3 = wT + 327680;
    B1 = rb1; B2 = rb2; B3 = rb3;
  }
#pragma unroll
  for (int k = 0; k < 4; ++k) {
    int e = tid + k * 512;
    int r = e >> 8, c = e & 255;
    int rowid = base + r;
    int b, rr;
    if (rowid < 1600) { b = rowid / 100; rr = rowid % 100; }
    else { int t2 = rowid - 1600; b = t2 / 25; rr = t2 % 25; }
    int n = idx[b * 100 + rr];
    actA[r][c] = x[((size_t)b * C_DIM + c) * N_PIX + n] + pos_bilinear(pe, c, n);
  }
  __syncthreads();
  mlp6_layer(actA, actB, red, W1, B1, true,  og, rg, tid);
  mlp6_layer(actB, actA, red, W2, B2, true,  og, rg, tid);
  mlp6_layer(actA, actB, red, W3, B3, false, og, rg, tid);
#pragma unroll
  for (int k = 0; k < 4; ++k) {
    int e = tid + k * 512;
    int r = e >> 8, o = e & 255;
    int rowid = base + r;
    if (rowid < 1600) {
      int rr = rowid % 100;
      det[(size_t)rowid * C_DIM + o] = actB[r][o] + det_q[rr * C_DIM + o];
    } else {
      int t2 = rowid - 1600; int rr = t2 % 25;
      rec[(size_t)t2 * C_DIM + o] = actB[r][o] + rec_q[rr * C_DIM + o];
    }
  }
}

extern "C" void kernel_launch(void* const* d_in, const int* in_sizes, int n_in,
                              void* d_out, int out_size, void* d_ws, size_t ws_size,
                              hipStream_t stream) {
  const float* x     = (const float*)d_in[0];
  const float* Wc    = (const float*)d_in[1];
  const float* bc    = (const float*)d_in[2];
  const float* Wb    = (const float*)d_in[3];
  const float* bb    = (const float*)d_in[4];
  const float* dW1   = (const float*)d_in[5];
  const float* db1   = (const float*)d_in[6];
  const float* dW2   = (const float*)d_in[7];
  const float* db2   = (const float*)d_in[8];
  const float* dW3   = (const float*)d_in[9];
  const float* db3   = (const float*)d_in[10];
  const float* rW1   = (const float*)d_in[11];
  const float* rb1   = (const float*)d_in[12];
  const float* rW2   = (const float*)d_in[13];
  const float* rb2   = (const float*)d_in[14];
  const float* rW3   = (const float*)d_in[15];
  const float* rb3   = (const float*)d_in[16];
  const float* det_q = (const float*)d_in[17];
  const float* rec_q = (const float*)d_in[18];
  const float* pos_e = (const float*)d_in[19];

  float* out  = (float*)d_out;
  float* det  = out;                // [16,100,256]
  float* rec  = out + 409600;       // [16, 25,256]
  float* cls  = out + 512000;       // [16,10000,2]
  float* bbox = out + 832000;       // [16,10000,4]

  // ws layout (bytes): wT @0 (1572864) | conf @1572864 (640000) | idx @2212864 | wpe @2221056
  char* wsb = (char*)d_ws;
  float* wT   = (float*)wsb;
  float* conf = (float*)(wsb + 1572864);
  int*   idx  = (int*)(wsb + 2212864);
  float* wpe  = (float*)(wsb + 2221056);

  k_prep_wpe<<<60, 256, 0, stream>>>(pos_e, Wc, Wb, wpe);
  k_heads4<<<dim3(40, B_SZ), 256, 0, stream>>>(x, wpe, Wc, bc, Wb, bb, cls, bbox, conf);
  k_topk_plus<<<112, 1024, 0, stream>>>(conf, idx, dW1, dW2, dW3, rW1, rW2, rW3, wT);
  k_mlp6<<<250, 512, 0, stream>>>(x, pos_e, idx, wT,
                                  db1, db2, db3, rb1, rb2, rb3,
                                  det_q, rec_q, det, rec);
}

// Round 21
// 101.754 us; speedup vs baseline: 2.1684x; 1.0613x over previous
//
#include <hip/hip_runtime.h>
#include <cstdint>
#include <cstddef>

#define C_DIM 256
#define N_PIX 10000
#define B_SZ 16

typedef float f32x4 __attribute__((ext_vector_type(4)));
typedef short s16x8 __attribute__((ext_vector_type(8)));

__device__ __forceinline__ unsigned short f2bf(float f) {
  unsigned int u = __float_as_uint(f);
  u += 0x7FFFu + ((u >> 16) & 1u);          // round-to-nearest-even
  return (unsigned short)(u >> 16);
}

// ---------------- k_prep_wpe (R15-exact) ------------------------------------------------
__global__ __launch_bounds__(256) void k_prep_wpe(
    const float* __restrict__ pe,
    const float* __restrict__ Wc, const float* __restrict__ Wb,
    float* __restrict__ wpe) {
  int tid = threadIdx.x;
  int bid = blockIdx.x;                 // 60 blocks
  int o = bid / 10;
  int p = (bid % 10) * 256 + tid;
  if (p >= 2500) return;
  const float* W = (o < 2) ? (Wc + o * C_DIM) : (Wb + (o - 2) * C_DIM);
  float acc = 0.f;
#pragma unroll 8
  for (int c = 0; c < C_DIM; ++c) acc = fmaf(W[c], pe[c * 2500 + p], acc);
  wpe[o * 2500 + p] = acc;
}

// ---------------- k_heads4 (R15-exact) --------------------------------------------------
__global__ __launch_bounds__(256, 4) void k_heads4(
    const float* __restrict__ x, const float* __restrict__ wpe,
    const float* __restrict__ Wc, const float* __restrict__ bc,
    const float* __restrict__ Wb, const float* __restrict__ bb,
    float* __restrict__ cls, float* __restrict__ bbox, float* __restrict__ conf) {
  int tid = threadIdx.x;
  int b = blockIdx.y;
  int n = blockIdx.x * 256 + tid;
  if (n >= N_PIX) return;
  const float* xb = x + (size_t)b * C_DIM * N_PIX + n;
  const float* w1p = Wc + C_DIM;
  const float* w2p = Wb;
  const float* w3p = Wb + C_DIM;
  const float* w4p = Wb + 2 * C_DIM;
  const float* w5p = Wb + 3 * C_DIM;
  float a0 = 0.f, a1 = 0.f, a2 = 0.f, a3 = 0.f, a4 = 0.f, a5 = 0.f;
  for (int c = 0; c < C_DIM; c += 16) {
    float xv[16];
#pragma unroll
    for (int j = 0; j < 16; ++j) xv[j] = xb[(size_t)(c + j) * N_PIX];
#pragma unroll
    for (int j = 0; j < 16; ++j) {
      float v = xv[j];
      a0 = fmaf(Wc[c + j],  v, a0);
      a1 = fmaf(w1p[c + j], v, a1);
      a2 = fmaf(w2p[c + j], v, a2);
      a3 = fmaf(w3p[c + j], v, a3);
      a4 = fmaf(w4p[c + j], v, a4);
      a5 = fmaf(w5p[c + j], v, a5);
    }
  }
  int y = n / 100, xq = n % 100;
  float sy = fminf(fmaxf((y + 0.5f) * 0.5f - 0.5f, 0.0f), 49.0f);
  float sx = fminf(fmaxf((xq + 0.5f) * 0.5f - 0.5f, 0.0f), 49.0f);
  int y0 = (int)floorf(sy); int y1 = min(y0 + 1, 49); float ty = sy - (float)y0;
  int x0i = (int)floorf(sx); int x1i = min(x0i + 1, 49); float tx = sx - (float)x0i;
  float pd[6];
#pragma unroll
  for (int o = 0; o < 6; ++o) {
    const float* m = wpe + o * 2500;
    float v00 = m[y0 * 50 + x0i], v01 = m[y0 * 50 + x1i];
    float v10 = m[y1 * 50 + x0i], v11 = m[y1 * 50 + x1i];
    float r0 = v00 * (1.0f - ty) + v10 * ty;
    float r1 = v01 * (1.0f - ty) + v11 * ty;
    pd[o] = r0 * (1.0f - tx) + r1 * tx;
  }
  float c0 = a0 + pd[0] + bc[0];
  float c1 = a1 + pd[1] + bc[1];
  float b0 = a2 + pd[2] + bb[0];
  float b1 = a3 + pd[3] + bb[1];
  float b2 = a4 + pd[4] + bb[2];
  float b3 = a5 + pd[5] + bb[3];
  size_t nb = (size_t)b * N_PIX + n;
  float2 cv; cv.x = c0; cv.y = c1;
  *(float2*)(cls + nb * 2) = cv;
  float4 bv; bv.x = b0; bv.y = b1; bv.z = b2; bv.w = b3;
  *(float4*)(bbox + nb * 4) = bv;
  float m0 = fmaxf(c0, c1);
  float e0 = expf(c0 - m0), e1 = expf(c1 - m0);
  conf[nb] = e1 / (e0 + e1);
}

// ---------------- k_topk_plus: blocks 0..15 top-k (R15-exact body) ----------------------
//                  blocks 16..111: bf16 B-fragment weight pack for k_mlp7
__global__ __launch_bounds__(1024) void k_topk_plus(
    const float* __restrict__ conf, int* __restrict__ idx_out,
    const float* __restrict__ dW1, const float* __restrict__ dW2, const float* __restrict__ dW3,
    const float* __restrict__ rW1, const float* __restrict__ rW2, const float* __restrict__ rW3,
    unsigned short* __restrict__ wB) {
  int tid = threadIdx.x;
  int bid = blockIdx.x;
  if (bid >= 16) {
    // pack: wB[m][ct][kc][lane][j] = bf16(W[ct*16 + (lane&15)][kc*32 + (lane>>4)*8 + j])
    int t = bid - 16;                 // 96 blocks: 6 matrices x 16 col-tiles
    int m = t >> 4;
    int ct = t & 15;
    const float* W;
    switch (m) {
      case 0: W = dW1; break;
      case 1: W = dW2; break;
      case 2: W = dW3; break;
      case 3: W = rW1; break;
      case 4: W = rW2; break;
      default: W = rW3; break;
    }
    if (tid < 512) {
      int kc = tid >> 6, lane = tid & 63;
      int o = ct * 16 + (lane & 15);
      int kb = kc * 32 + (lane >> 4) * 8;
      float4 f0 = *(const float4*)(W + (size_t)o * 256 + kb);
      float4 f1 = *(const float4*)(W + (size_t)o * 256 + kb + 4);
      s16x8 v;
      v[0] = (short)f2bf(f0.x); v[1] = (short)f2bf(f0.y);
      v[2] = (short)f2bf(f0.z); v[3] = (short)f2bf(f0.w);
      v[4] = (short)f2bf(f1.x); v[5] = (short)f2bf(f1.y);
      v[6] = (short)f2bf(f1.z); v[7] = (short)f2bf(f1.w);
      *(s16x8*)(wB + (size_t)m * 65536 + ((size_t)(ct * 8 + kc) * 64 + lane) * 8) = v;
    }
    return;
  }
  __shared__ unsigned int ord[N_PIX];
  __shared__ unsigned int whist[16][256];
  __shared__ unsigned int sfx[256];
  __shared__ unsigned long long cand[512];
  __shared__ unsigned int s_cnt, s_prefix, s_ncand;
  int wv = tid >> 6;
  int b = bid;
  const float* cb = conf + (size_t)b * N_PIX;
  for (int i = tid; i < N_PIX; i += 1024) {
    unsigned int u = __float_as_uint(cb[i]);
    ord[i] = (u & 0x80000000u) ? ~u : (u | 0x80000000u);
  }
  unsigned int prefix = 0, cnt_gt = 0;
  for (int pass = 0; pass < 4; ++pass) {
    int sh = 24 - 8 * pass;
    for (int i = tid; i < 16 * 256; i += 1024) ((unsigned int*)whist)[i] = 0;
    __syncthreads();
    unsigned int himask = (pass == 0) ? 0u : (0xFFFFFFFFu << (sh + 8));
    for (int i = tid; i < N_PIX; i += 1024) {
      unsigned int o = ord[i];
      if ((o & himask) == prefix) atomicAdd(&whist[wv][(o >> sh) & 255u], 1u);
    }
    __syncthreads();
    if (tid < 256) {
      unsigned int s = 0;
#pragma unroll
      for (int w2 = 0; w2 < 16; ++w2) s += whist[w2][tid];
      sfx[tid] = s;
    }
    __syncthreads();
#pragma unroll
    for (int off = 1; off < 256; off <<= 1) {
      unsigned int add = 0;
      if (tid < 256 && tid + off < 256) add = sfx[tid + off];
      __syncthreads();
      if (tid < 256) sfx[tid] += add;
      __syncthreads();
    }
    if (tid < 256) {
      unsigned int Sv = sfx[tid];
      unsigned int Sn = (tid < 255) ? sfx[tid + 1] : 0u;
      if (cnt_gt + Sv >= 100u && (tid == 255 || cnt_gt + Sn < 100u)) {
        s_cnt = cnt_gt + Sn;
        s_prefix = prefix | ((unsigned int)tid << sh);
      }
    }
    __syncthreads();
    cnt_gt = s_cnt; prefix = s_prefix;
    __syncthreads();
  }
  if (tid == 0) s_ncand = 0;
  __syncthreads();
  unsigned int T = prefix;
  for (int i = tid; i < N_PIX; i += 1024) {
    unsigned int o = ord[i];
    if (o >= T) {
      unsigned int k = atomicAdd(&s_ncand, 1u);
      if (k < 512u)
        cand[k] = ((unsigned long long)o << 32) |
                  (unsigned long long)(0xFFFFFFFFu - (unsigned int)i);
    }
  }
  __syncthreads();
  unsigned int nc = s_ncand > 512u ? 512u : s_ncand;
  for (int i = tid; i < 512; i += 1024)
    if ((unsigned int)i >= nc) cand[i] = 0ull;
  __syncthreads();
  for (unsigned int k = 2; k <= 512; k <<= 1) {
    for (unsigned int j = k >> 1; j > 0; j >>= 1) {
      if (tid < 512) {
        unsigned int i = (unsigned int)tid, ixj = i ^ j;
        if (ixj > i) {
          unsigned long long a = cand[i], c2 = cand[ixj];
          bool up = ((i & k) == 0);
          if ((a > c2) == up) { cand[i] = c2; cand[ixj] = a; }
        }
      }
      __syncthreads();
    }
  }
  if (tid < 100) {
    unsigned long long key = cand[511 - tid];
    idx_out[b * 100 + tid] = (int)(0xFFFFFFFFu - (unsigned int)(key & 0xFFFFFFFFull));
  }
}

// ---------------- k_mlp7: MFMA bf16 MLP. 125 blocks x 512 thr; 16 rows/block ------------
#define APAD 260

__device__ __forceinline__ float pos_bilinear(const float* __restrict__ pe, int c, int n) {
  int y = n / 100, xq = n % 100;
  float sy = fminf(fmaxf((y + 0.5f) * 0.5f - 0.5f, 0.0f), 49.0f);
  float sx = fminf(fmaxf((xq + 0.5f) * 0.5f - 0.5f, 0.0f), 49.0f);
  int y0 = (int)floorf(sy); int y1 = min(y0 + 1, 49); float ty = sy - (float)y0;
  int x0i = (int)floorf(sx); int x1i = min(x0i + 1, 49); float tx = sx - (float)x0i;
  const float* p = pe + (size_t)c * 2500;
  float v00 = p[y0 * 50 + x0i], v01 = p[y0 * 50 + x1i];
  float v10 = p[y1 * 50 + x0i], v11 = p[y1 * 50 + x1i];
  float rr0 = v00 * (1.0f - ty) + v10 * ty;
  float rr1 = v01 * (1.0f - ty) + v11 * ty;
  return rr0 * (1.0f - tx) + rr1 * tx;
}

// one layer: out[r][o] = act(in[r][:] @ W + bias). Wave wv handles col-tiles 2wv, 2wv+1.
__device__ __forceinline__ void mfma_layer(
    const float (*in)[APAD], float (*out)[APAD],
    const unsigned short* __restrict__ W, const float* __restrict__ bias,
    bool relu, int lane, int wv) {
  int row_a = lane & 15, kg = lane >> 4;
  int ct0 = wv * 2, ct1 = wv * 2 + 1;
  f32x4 acc0 = {0.f, 0.f, 0.f, 0.f}, acc1 = {0.f, 0.f, 0.f, 0.f};
#pragma unroll
  for (int kc = 0; kc < 8; ++kc) {
    int k0 = kc * 32 + kg * 8;
    float4 fa = *(const float4*)(&in[row_a][k0]);
    float4 fb = *(const float4*)(&in[row_a][k0 + 4]);
    s16x8 a;
    a[0] = (short)f2bf(fa.x); a[1] = (short)f2bf(fa.y);
    a[2] = (short)f2bf(fa.z); a[3] = (short)f2bf(fa.w);
    a[4] = (short)f2bf(fb.x); a[5] = (short)f2bf(fb.y);
    a[6] = (short)f2bf(fb.z); a[7] = (short)f2bf(fb.w);
    s16x8 b0 = *(const s16x8*)(W + ((size_t)(ct0 * 8 + kc) * 64 + lane) * 8);
    s16x8 b1 = *(const s16x8*)(W + ((size_t)(ct1 * 8 + kc) * 64 + lane) * 8);
    acc0 = __builtin_amdgcn_mfma_f32_16x16x32_bf16(a, b0, acc0, 0, 0, 0);
    acc1 = __builtin_amdgcn_mfma_f32_16x16x32_bf16(a, b1, acc1, 0, 0, 0);
  }
  int col = lane & 15;
#pragma unroll
  for (int r = 0; r < 4; ++r) {
    int row_d = kg * 4 + r;
    int o0 = ct0 * 16 + col, o1 = ct1 * 16 + col;
    float v0 = acc0[r] + bias[o0];
    float v1 = acc1[r] + bias[o1];
    out[row_d][o0] = relu ? fmaxf(v0, 0.f) : v0;
    out[row_d][o1] = relu ? fmaxf(v1, 0.f) : v1;
  }
}

__global__ __launch_bounds__(512, 2) void k_mlp7(
    const float* __restrict__ x, const float* __restrict__ pe, const int* __restrict__ idx,
    const unsigned short* __restrict__ wB,
    const float* __restrict__ db1, const float* __restrict__ db2, const float* __restrict__ db3,
    const float* __restrict__ rb1, const float* __restrict__ rb2, const float* __restrict__ rb3,
    const float* __restrict__ det_q, const float* __restrict__ rec_q,
    float* __restrict__ det, float* __restrict__ rec) {
  __shared__ float actA[16][APAD];
  __shared__ float actB[16][APAD];
  int tid = threadIdx.x;
  int lane = tid & 63, wv = tid >> 6;
  int base = blockIdx.x * 16;          // 125 blocks; blocks 0..99 det, 100..124 rec
  bool is_det = base < 1600;
  const unsigned short *W1, *W2, *W3;
  const float *B1, *B2, *B3;
  if (is_det) {
    W1 = wB;          W2 = wB + 65536;  W3 = wB + 131072;
    B1 = db1; B2 = db2; B3 = db3;
  } else {
    W1 = wB + 196608; W2 = wB + 262144; W3 = wB + 327680;
    B1 = rb1; B2 = rb2; B3 = rb3;
  }
  // gather: 4096 elements, thread handles 8
#pragma unroll
  for (int k = 0; k < 8; ++k) {
    int e = tid + k * 512;
    int r = e >> 8, c = e & 255;
    int rowid = base + r;
    int b, rr;
    if (rowid < 1600) { b = rowid / 100; rr = rowid % 100; }
    else { int t2 = rowid - 1600; b = t2 / 25; rr = t2 % 25; }
    int n = idx[b * 100 + rr];
    actA[r][c] = x[((size_t)b * C_DIM + c) * N_PIX + n] + pos_bilinear(pe, c, n);
  }
  __syncthreads();
  mfma_layer(actA, actB, W1, B1, true, lane, wv);
  __syncthreads();
  mfma_layer(actB, actA, W2, B2, true, lane, wv);
  __syncthreads();
  // final layer: MFMA then write straight to det/rec with query embed
  {
    int row_a = lane & 15, kg = lane >> 4;
    int ct0 = wv * 2, ct1 = wv * 2 + 1;
    f32x4 acc0 = {0.f, 0.f, 0.f, 0.f}, acc1 = {0.f, 0.f, 0.f, 0.f};
#pragma unroll
    for (int kc = 0; kc < 8; ++kc) {
      int k0 = kc * 32 + kg * 8;
      float4 fa = *(const float4*)(&actA[row_a][k0]);
      float4 fb = *(const float4*)(&actA[row_a][k0 + 4]);
      s16x8 a;
      a[0] = (short)f2bf(fa.x); a[1] = (short)f2bf(fa.y);
      a[2] = (short)f2bf(fa.z); a[3] = (short)f2bf(fa.w);
      a[4] = (short)f2bf(fb.x); a[5] = (short)f2bf(fb.y);
      a[6] = (short)f2bf(fb.z); a[7] = (short)f2bf(fb.w);
      s16x8 b0 = *(const s16x8*)(W3 + ((size_t)(ct0 * 8 + kc) * 64 + lane) * 8);
      s16x8 b1 = *(const s16x8*)(W3 + ((size_t)(ct1 * 8 + kc) * 64 + lane) * 8);
      acc0 = __builtin_amdgcn_mfma_f32_16x16x32_bf16(a, b0, acc0, 0, 0, 0);
      acc1 = __builtin_amdgcn_mfma_f32_16x16x32_bf16(a, b1, acc1, 0, 0, 0);
    }
    int col = lane & 15;
#pragma unroll
    for (int r = 0; r < 4; ++r) {
      int row_d = kg * 4 + r;
      int rowid = base + row_d;
#pragma unroll
      for (int q = 0; q < 2; ++q) {
        int ct = (q == 0) ? ct0 : ct1;
        int o = ct * 16 + col;
        float v = ((q == 0) ? acc0[r] : acc1[r]) + B3[o];
        if (rowid < 1600) {
          det[(size_t)rowid * 256 + o] = v + det_q[(rowid % 100) * 256 + o];
        } else {
          int t2 = rowid - 1600;
          rec[(size_t)t2 * 256 + o] = v + rec_q[(t2 % 25) * 256 + o];
        }
      }
    }
  }
}

extern "C" void kernel_launch(void* const* d_in, const int* in_sizes, int n_in,
                              void* d_out, int out_size, void* d_ws, size_t ws_size,
                              hipStream_t stream) {
  const float* x     = (const float*)d_in[0];
  const float* Wc    = (const float*)d_in[1];
  const float* bc    = (const float*)d_in[2];
  const float* Wb    = (const float*)d_in[3];
  const float* bb    = (const float*)d_in[4];
  const float* dW1   = (const float*)d_in[5];
  const float* db1   = (const float*)d_in[6];
  const float* dW2   = (const float*)d_in[7];
  const float* db2   = (const float*)d_in[8];
  const float* dW3   = (const float*)d_in[9];
  const float* db3   = (const float*)d_in[10];
  const float* rW1   = (const float*)d_in[11];
  const float* rb1   = (const float*)d_in[12];
  const float* rW2   = (const float*)d_in[13];
  const float* rb2   = (const float*)d_in[14];
  const float* rW3   = (const float*)d_in[15];
  const float* rb3   = (const float*)d_in[16];
  const float* det_q = (const float*)d_in[17];
  const float* rec_q = (const float*)d_in[18];
  const float* pos_e = (const float*)d_in[19];

  float* out  = (float*)d_out;
  float* det  = out;                // [16,100,256]
  float* rec  = out + 409600;       // [16, 25,256]
  float* cls  = out + 512000;       // [16,10000,2]
  float* bbox = out + 832000;       // [16,10000,4]

  // ws (bytes): wB bf16[6*65536] @0 (786432) | conf @786432 (640000)
  //             idx @1426432 (8192) | wpe @1434624 (60000)
  char* wsb = (char*)d_ws;
  unsigned short* wB = (unsigned short*)wsb;
  float* conf = (float*)(wsb + 786432);
  int*   idx  = (int*)(wsb + 1426432);
  float* wpe  = (float*)(wsb + 1434624);

  k_prep_wpe<<<60, 256, 0, stream>>>(pos_e, Wc, Wb, wpe);
  k_heads4<<<dim3(40, B_SZ), 256, 0, stream>>>(x, wpe, Wc, bc, Wb, bb, cls, bbox, conf);
  k_topk_plus<<<112, 1024, 0, stream>>>(conf, idx, dW1, dW2, dW3, rW1, rW2, rW3, wB);
  k_mlp7<<<125, 512, 0, stream>>>(x, pos_e, idx, wB,
                                  db1, db2, db3, rb1, rb2, rb3,
                                  det_q, rec_q, det, rec);
}

// Round 22
// 99.444 us; speedup vs baseline: 2.2188x; 1.0232x over previous
//
#include <hip/hip_runtime.h>
#include <cstdint>
#include <cstddef>

#define C_DIM 256
#define N_PIX 10000
#define B_SZ 16

typedef float f32x4 __attribute__((ext_vector_type(4)));
typedef short s16x8 __attribute__((ext_vector_type(8)));

__device__ __forceinline__ unsigned short f2bf(float f) {
  unsigned int u = __float_as_uint(f);
  u += 0x7FFFu + ((u >> 16) & 1u);          // round-to-nearest-even
  return (unsigned short)(u >> 16);
}

// ---------------- k_prep_wpe (R21-exact) ------------------------------------------------
__global__ __launch_bounds__(256) void k_prep_wpe(
    const float* __restrict__ pe,
    const float* __restrict__ Wc, const float* __restrict__ Wb,
    float* __restrict__ wpe) {
  int tid = threadIdx.x;
  int bid = blockIdx.x;                 // 60 blocks
  int o = bid / 10;
  int p = (bid % 10) * 256 + tid;
  if (p >= 2500) return;
  const float* W = (o < 2) ? (Wc + o * C_DIM) : (Wb + (o - 2) * C_DIM);
  float acc = 0.f;
#pragma unroll 8
  for (int c = 0; c < C_DIM; ++c) acc = fmaf(W[c], pe[c * 2500 + p], acc);
  wpe[o * 2500 + p] = acc;
}

// ---------------- k_heads4 (R21-exact) --------------------------------------------------
__global__ __launch_bounds__(256, 4) void k_heads4(
    const float* __restrict__ x, const float* __restrict__ wpe,
    const float* __restrict__ Wc, const float* __restrict__ bc,
    const float* __restrict__ Wb, const float* __restrict__ bb,
    float* __restrict__ cls, float* __restrict__ bbox, float* __restrict__ conf) {
  int tid = threadIdx.x;
  int b = blockIdx.y;
  int n = blockIdx.x * 256 + tid;
  if (n >= N_PIX) return;
  const float* xb = x + (size_t)b * C_DIM * N_PIX + n;
  const float* w1p = Wc + C_DIM;
  const float* w2p = Wb;
  const float* w3p = Wb + C_DIM;
  const float* w4p = Wb + 2 * C_DIM;
  const float* w5p = Wb + 3 * C_DIM;
  float a0 = 0.f, a1 = 0.f, a2 = 0.f, a3 = 0.f, a4 = 0.f, a5 = 0.f;
  for (int c = 0; c < C_DIM; c += 16) {
    float xv[16];
#pragma unroll
    for (int j = 0; j < 16; ++j) xv[j] = xb[(size_t)(c + j) * N_PIX];
#pragma unroll
    for (int j = 0; j < 16; ++j) {
      float v = xv[j];
      a0 = fmaf(Wc[c + j],  v, a0);
      a1 = fmaf(w1p[c + j], v, a1);
      a2 = fmaf(w2p[c + j], v, a2);
      a3 = fmaf(w3p[c + j], v, a3);
      a4 = fmaf(w4p[c + j], v, a4);
      a5 = fmaf(w5p[c + j], v, a5);
    }
  }
  int y = n / 100, xq = n % 100;
  float sy = fminf(fmaxf((y + 0.5f) * 0.5f - 0.5f, 0.0f), 49.0f);
  float sx = fminf(fmaxf((xq + 0.5f) * 0.5f - 0.5f, 0.0f), 49.0f);
  int y0 = (int)floorf(sy); int y1 = min(y0 + 1, 49); float ty = sy - (float)y0;
  int x0i = (int)floorf(sx); int x1i = min(x0i + 1, 49); float tx = sx - (float)x0i;
  float pd[6];
#pragma unroll
  for (int o = 0; o < 6; ++o) {
    const float* m = wpe + o * 2500;
    float v00 = m[y0 * 50 + x0i], v01 = m[y0 * 50 + x1i];
    float v10 = m[y1 * 50 + x0i], v11 = m[y1 * 50 + x1i];
    float r0 = v00 * (1.0f - ty) + v10 * ty;
    float r1 = v01 * (1.0f - ty) + v11 * ty;
    pd[o] = r0 * (1.0f - tx) + r1 * tx;
  }
  float c0 = a0 + pd[0] + bc[0];
  float c1 = a1 + pd[1] + bc[1];
  float b0 = a2 + pd[2] + bb[0];
  float b1 = a3 + pd[3] + bb[1];
  float b2 = a4 + pd[4] + bb[2];
  float b3 = a5 + pd[5] + bb[3];
  size_t nb = (size_t)b * N_PIX + n;
  float2 cv; cv.x = c0; cv.y = c1;
  *(float2*)(cls + nb * 2) = cv;
  float4 bv; bv.x = b0; bv.y = b1; bv.z = b2; bv.w = b3;
  *(float4*)(bbox + nb * 4) = bv;
  float m0 = fmaxf(c0, c1);
  float e0 = expf(c0 - m0), e1 = expf(c1 - m0);
  conf[nb] = e1 / (e0 + e1);
}

// ---------------- k_topk_plus (R21-exact): top-k + bf16 weight pack ride-along ----------
__global__ __launch_bounds__(1024) void k_topk_plus(
    const float* __restrict__ conf, int* __restrict__ idx_out,
    const float* __restrict__ dW1, const float* __restrict__ dW2, const float* __restrict__ dW3,
    const float* __restrict__ rW1, const float* __restrict__ rW2, const float* __restrict__ rW3,
    unsigned short* __restrict__ wB) {
  int tid = threadIdx.x;
  int bid = blockIdx.x;
  if (bid >= 16) {
    int t = bid - 16;                 // 96 blocks: 6 matrices x 16 col-tiles
    int m = t >> 4;
    int ct = t & 15;
    const float* W;
    switch (m) {
      case 0: W = dW1; break;
      case 1: W = dW2; break;
      case 2: W = dW3; break;
      case 3: W = rW1; break;
      case 4: W = rW2; break;
      default: W = rW3; break;
    }
    if (tid < 512) {
      int kc = tid >> 6, lane = tid & 63;
      int o = ct * 16 + (lane & 15);
      int kb = kc * 32 + (lane >> 4) * 8;
      float4 f0 = *(const float4*)(W + (size_t)o * 256 + kb);
      float4 f1 = *(const float4*)(W + (size_t)o * 256 + kb + 4);
      s16x8 v;
      v[0] = (short)f2bf(f0.x); v[1] = (short)f2bf(f0.y);
      v[2] = (short)f2bf(f0.z); v[3] = (short)f2bf(f0.w);
      v[4] = (short)f2bf(f1.x); v[5] = (short)f2bf(f1.y);
      v[6] = (short)f2bf(f1.z); v[7] = (short)f2bf(f1.w);
      *(s16x8*)(wB + (size_t)m * 65536 + ((size_t)(ct * 8 + kc) * 64 + lane) * 8) = v;
    }
    return;
  }
  __shared__ unsigned int ord[N_PIX];
  __shared__ unsigned int whist[16][256];
  __shared__ unsigned int sfx[256];
  __shared__ unsigned long long cand[512];
  __shared__ unsigned int s_cnt, s_prefix, s_ncand;
  int wv = tid >> 6;
  int b = bid;
  const float* cb = conf + (size_t)b * N_PIX;
  for (int i = tid; i < N_PIX; i += 1024) {
    unsigned int u = __float_as_uint(cb[i]);
    ord[i] = (u & 0x80000000u) ? ~u : (u | 0x80000000u);
  }
  unsigned int prefix = 0, cnt_gt = 0;
  for (int pass = 0; pass < 4; ++pass) {
    int sh = 24 - 8 * pass;
    for (int i = tid; i < 16 * 256; i += 1024) ((unsigned int*)whist)[i] = 0;
    __syncthreads();
    unsigned int himask = (pass == 0) ? 0u : (0xFFFFFFFFu << (sh + 8));
    for (int i = tid; i < N_PIX; i += 1024) {
      unsigned int o = ord[i];
      if ((o & himask) == prefix) atomicAdd(&whist[wv][(o >> sh) & 255u], 1u);
    }
    __syncthreads();
    if (tid < 256) {
      unsigned int s = 0;
#pragma unroll
      for (int w2 = 0; w2 < 16; ++w2) s += whist[w2][tid];
      sfx[tid] = s;
    }
    __syncthreads();
#pragma unroll
    for (int off = 1; off < 256; off <<= 1) {
      unsigned int add = 0;
      if (tid < 256 && tid + off < 256) add = sfx[tid + off];
      __syncthreads();
      if (tid < 256) sfx[tid] += add;
      __syncthreads();
    }
    if (tid < 256) {
      unsigned int Sv = sfx[tid];
      unsigned int Sn = (tid < 255) ? sfx[tid + 1] : 0u;
      if (cnt_gt + Sv >= 100u && (tid == 255 || cnt_gt + Sn < 100u)) {
        s_cnt = cnt_gt + Sn;
        s_prefix = prefix | ((unsigned int)tid << sh);
      }
    }
    __syncthreads();
    cnt_gt = s_cnt; prefix = s_prefix;
    __syncthreads();
  }
  if (tid == 0) s_ncand = 0;
  __syncthreads();
  unsigned int T = prefix;
  for (int i = tid; i < N_PIX; i += 1024) {
    unsigned int o = ord[i];
    if (o >= T) {
      unsigned int k = atomicAdd(&s_ncand, 1u);
      if (k < 512u)
        cand[k] = ((unsigned long long)o << 32) |
                  (unsigned long long)(0xFFFFFFFFu - (unsigned int)i);
    }
  }
  __syncthreads();
  unsigned int nc = s_ncand > 512u ? 512u : s_ncand;
  for (int i = tid; i < 512; i += 1024)
    if ((unsigned int)i >= nc) cand[i] = 0ull;
  __syncthreads();
  for (unsigned int k = 2; k <= 512; k <<= 1) {
    for (unsigned int j = k >> 1; j > 0; j >>= 1) {
      if (tid < 512) {
        unsigned int i = (unsigned int)tid, ixj = i ^ j;
        if (ixj > i) {
          unsigned long long a = cand[i], c2 = cand[ixj];
          bool up = ((i & k) == 0);
          if ((a > c2) == up) { cand[i] = c2; cand[ixj] = a; }
        }
      }
      __syncthreads();
    }
  }
  if (tid < 100) {
    unsigned long long key = cand[511 - tid];
    idx_out[b * 100 + tid] = (int)(0xFFFFFFFFu - (unsigned int)(key & 0xFFFFFFFFull));
  }
}

// ---------------- k_gather: act[row][c] = x[b][c][n] + pos; 500 blocks x 4 rows ---------
__device__ __forceinline__ float pos_bilinear(const float* __restrict__ pe, int c, int n) {
  int y = n / 100, xq = n % 100;
  float sy = fminf(fmaxf((y + 0.5f) * 0.5f - 0.5f, 0.0f), 49.0f);
  float sx = fminf(fmaxf((xq + 0.5f) * 0.5f - 0.5f, 0.0f), 49.0f);
  int y0 = (int)floorf(sy); int y1 = min(y0 + 1, 49); float ty = sy - (float)y0;
  int x0i = (int)floorf(sx); int x1i = min(x0i + 1, 49); float tx = sx - (float)x0i;
  const float* p = pe + (size_t)c * 2500;
  float v00 = p[y0 * 50 + x0i], v01 = p[y0 * 50 + x1i];
  float v10 = p[y1 * 50 + x0i], v11 = p[y1 * 50 + x1i];
  float rr0 = v00 * (1.0f - ty) + v10 * ty;
  float rr1 = v01 * (1.0f - ty) + v11 * ty;
  return rr0 * (1.0f - tx) + rr1 * tx;
}

__global__ __launch_bounds__(256) void k_gather(
    const float* __restrict__ x, const float* __restrict__ pe, const int* __restrict__ idx,
    float* __restrict__ act) {
  int tid = threadIdx.x;
  int base = blockIdx.x * 4;            // 500 blocks -> rows 0..1999
#pragma unroll
  for (int lr = 0; lr < 4; ++lr) {
    int rowid = base + lr;
    int b, r;
    if (rowid < 1600) { b = rowid / 100; r = rowid % 100; }
    else { int t2 = rowid - 1600; b = t2 / 25; r = t2 % 25; }
    int n = idx[b * 100 + r];
    act[(size_t)rowid * C_DIM + tid] =
        x[((size_t)b * C_DIM + tid) * N_PIX + n] + pos_bilinear(pe, tid, n);
  }
}

// ---------------- k_mlp7b: MFMA bf16 MLP over precomputed act. 125 blocks x 512 ---------
#define APAD 260

__device__ __forceinline__ void mfma_layer(
    const float (*in)[APAD], float (*out)[APAD],
    const unsigned short* __restrict__ W, const float* __restrict__ bias,
    bool relu, int lane, int wv) {
  int row_a = lane & 15, kg = lane >> 4;
  int ct0 = wv * 2, ct1 = wv * 2 + 1;
  f32x4 acc0 = {0.f, 0.f, 0.f, 0.f}, acc1 = {0.f, 0.f, 0.f, 0.f};
#pragma unroll
  for (int kc = 0; kc < 8; ++kc) {
    int k0 = kc * 32 + kg * 8;
    float4 fa = *(const float4*)(&in[row_a][k0]);
    float4 fb = *(const float4*)(&in[row_a][k0 + 4]);
    s16x8 a;
    a[0] = (short)f2bf(fa.x); a[1] = (short)f2bf(fa.y);
    a[2] = (short)f2bf(fa.z); a[3] = (short)f2bf(fa.w);
    a[4] = (short)f2bf(fb.x); a[5] = (short)f2bf(fb.y);
    a[6] = (short)f2bf(fb.z); a[7] = (short)f2bf(fb.w);
    s16x8 b0 = *(const s16x8*)(W + ((size_t)(ct0 * 8 + kc) * 64 + lane) * 8);
    s16x8 b1 = *(const s16x8*)(W + ((size_t)(ct1 * 8 + kc) * 64 + lane) * 8);
    acc0 = __builtin_amdgcn_mfma_f32_16x16x32_bf16(a, b0, acc0, 0, 0, 0);
    acc1 = __builtin_amdgcn_mfma_f32_16x16x32_bf16(a, b1, acc1, 0, 0, 0);
  }
  int col = lane & 15;
#pragma unroll
  for (int r = 0; r < 4; ++r) {
    int row_d = kg * 4 + r;
    int o0 = ct0 * 16 + col, o1 = ct1 * 16 + col;
    float v0 = acc0[r] + bias[o0];
    float v1 = acc1[r] + bias[o1];
    out[row_d][o0] = relu ? fmaxf(v0, 0.f) : v0;
    out[row_d][o1] = relu ? fmaxf(v1, 0.f) : v1;
  }
}

__global__ __launch_bounds__(512, 2) void k_mlp7b(
    const float* __restrict__ act,
    const unsigned short* __restrict__ wB,
    const float* __restrict__ db1, const float* __restrict__ db2, const float* __restrict__ db3,
    const float* __restrict__ rb1, const float* __restrict__ rb2, const float* __restrict__ rb3,
    const float* __restrict__ det_q, const float* __restrict__ rec_q,
    float* __restrict__ det, float* __restrict__ rec) {
  __shared__ float actA[16][APAD];
  __shared__ float actB[16][APAD];
  int tid = threadIdx.x;
  int lane = tid & 63, wv = tid >> 6;
  int base = blockIdx.x * 16;          // 125 blocks
  bool is_det = base < 1600;
  const unsigned short *W1, *W2, *W3;
  const float *B1, *B2, *B3;
  if (is_det) {
    W1 = wB;          W2 = wB + 65536;  W3 = wB + 131072;
    B1 = db1; B2 = db2; B3 = db3;
  } else {
    W1 = wB + 196608; W2 = wB + 262144; W3 = wB + 327680;
    B1 = rb1; B2 = rb2; B3 = rb3;
  }
  // load act rows coalesced (L2-hot, contiguous)
#pragma unroll
  for (int k = 0; k < 8; ++k) {
    int e = tid + k * 512;
    int r = e >> 8, c = e & 255;
    actA[r][c] = act[(size_t)(base + r) * C_DIM + c];
  }
  __syncthreads();
  mfma_layer(actA, actB, W1, B1, true, lane, wv);
  __syncthreads();
  mfma_layer(actB, actA, W2, B2, true, lane, wv);
  __syncthreads();
  {
    int row_a = lane & 15, kg = lane >> 4;
    int ct0 = wv * 2, ct1 = wv * 2 + 1;
    f32x4 acc0 = {0.f, 0.f, 0.f, 0.f}, acc1 = {0.f, 0.f, 0.f, 0.f};
#pragma unroll
    for (int kc = 0; kc < 8; ++kc) {
      int k0 = kc * 32 + kg * 8;
      float4 fa = *(const float4*)(&actA[row_a][k0]);
      float4 fb = *(const float4*)(&actA[row_a][k0 + 4]);
      s16x8 a;
      a[0] = (short)f2bf(fa.x); a[1] = (short)f2bf(fa.y);
      a[2] = (short)f2bf(fa.z); a[3] = (short)f2bf(fa.w);
      a[4] = (short)f2bf(fb.x); a[5] = (short)f2bf(fb.y);
      a[6] = (short)f2bf(fb.z); a[7] = (short)f2bf(fb.w);
      s16x8 b0 = *(const s16x8*)(W3 + ((size_t)(ct0 * 8 + kc) * 64 + lane) * 8);
      s16x8 b1 = *(const s16x8*)(W3 + ((size_t)(ct1 * 8 + kc) * 64 + lane) * 8);
      acc0 = __builtin_amdgcn_mfma_f32_16x16x32_bf16(a, b0, acc0, 0, 0, 0);
      acc1 = __builtin_amdgcn_mfma_f32_16x16x32_bf16(a, b1, acc1, 0, 0, 0);
    }
    int col = lane & 15;
#pragma unroll
    for (int r = 0; r < 4; ++r) {
      int row_d = kg * 4 + r;
      int rowid = base + row_d;
#pragma unroll
      for (int q = 0; q < 2; ++q) {
        int ct = (q == 0) ? ct0 : ct1;
        int o = ct * 16 + col;
        float v = ((q == 0) ? acc0[r] : acc1[r]) + B3[o];
        if (rowid < 1600) {
          det[(size_t)rowid * 256 + o] = v + det_q[(rowid % 100) * 256 + o];
        } else {
          int t2 = rowid - 1600;
          rec[(size_t)t2 * 256 + o] = v + rec_q[(t2 % 25) * 256 + o];
        }
      }
    }
  }
}

extern "C" void kernel_launch(void* const* d_in, const int* in_sizes, int n_in,
                              void* d_out, int out_size, void* d_ws, size_t ws_size,
                              hipStream_t stream) {
  const float* x     = (const float*)d_in[0];
  const float* Wc    = (const float*)d_in[1];
  const float* bc    = (const float*)d_in[2];
  const float* Wb    = (const float*)d_in[3];
  const float* bb    = (const float*)d_in[4];
  const float* dW1   = (const float*)d_in[5];
  const float* db1   = (const float*)d_in[6];
  const float* dW2   = (const float*)d_in[7];
  const float* db2   = (const float*)d_in[8];
  const float* dW3   = (const float*)d_in[9];
  const float* db3   = (const float*)d_in[10];
  const float* rW1   = (const float*)d_in[11];
  const float* rb1   = (const float*)d_in[12];
  const float* rW2   = (const float*)d_in[13];
  const float* rb2   = (const float*)d_in[14];
  const float* rW3   = (const float*)d_in[15];
  const float* rb3   = (const float*)d_in[16];
  const float* det_q = (const float*)d_in[17];
  const float* rec_q = (const float*)d_in[18];
  const float* pos_e = (const float*)d_in[19];

  float* out  = (float*)d_out;
  float* det  = out;                // [16,100,256]
  float* rec  = out + 409600;       // [16, 25,256]
  float* cls  = out + 512000;       // [16,10000,2]
  float* bbox = out + 832000;       // [16,10000,4]

  // ws (bytes): wB bf16[6*65536] @0 (786432) | conf @786432 (640000)
  //             idx @1426432 (8192) | wpe @1434624 (60000) | act @1494624 (2048000)
  char* wsb = (char*)d_ws;
  unsigned short* wB = (unsigned short*)wsb;
  float* conf = (float*)(wsb + 786432);
  int*   idx  = (int*)(wsb + 1426432);
  float* wpe  = (float*)(wsb + 1434624);
  float* act  = (float*)(wsb + 1494624);

  k_prep_wpe<<<60, 256, 0, stream>>>(pos_e, Wc, Wb, wpe);
  k_heads4<<<dim3(40, B_SZ), 256, 0, stream>>>(x, wpe, Wc, bc, Wb, bb, cls, bbox, conf);
  k_topk_plus<<<112, 1024, 0, stream>>>(conf, idx, dW1, dW2, dW3, rW1, rW2, rW3, wB);
  k_gather<<<500, 256, 0, stream>>>(x, pos_e, idx, act);
  k_mlp7b<<<125, 512, 0, stream>>>(act, wB,
                                   db1, db2, db3, rb1, rb2, rb3,
                                   det_q, rec_q, det, rec);
}